// Round 8
// baseline (336.016 us; speedup 1.0000x reference)
//
#include <hip/hip_runtime.h>
#include <hip/hip_bf16.h>

#define S_LEN  2048
#define DMODEL 2048
#define NH     32
#define NG     8
#define DK     64
#define DV     64

typedef short bf16x8 __attribute__((ext_vector_type(8)));
typedef float f32x4  __attribute__((ext_vector_type(4)));

__device__ __forceinline__ ushort f32_to_bf16(float f) {
    uint u = __float_as_uint(f);
    return (ushort)((u + 0x7fffu + ((u >> 16) & 1u)) >> 16);   // RNE
}

// ---------------------------------------------- cast f32->bf16, z = 0/1/2 input
__global__ void cast3_f32_to_bf16(const float* __restrict__ q,
                                  const float* __restrict__ k,
                                  const float* __restrict__ v,
                                  ushort* __restrict__ oq,
                                  ushort* __restrict__ ok,
                                  ushort* __restrict__ ov, int n8) {
    const float* in = blockIdx.z == 0 ? q : (blockIdx.z == 1 ? k : v);
    ushort* out     = blockIdx.z == 0 ? oq : (blockIdx.z == 1 ? ok : ov);
    int i = blockIdx.x * blockDim.x + threadIdx.x;
    const int stride = gridDim.x * blockDim.x;
    for (; i < n8; i += stride) {
        const float4 a = ((const float4*)in)[2 * i];
        const float4 b = ((const float4*)in)[2 * i + 1];
        uint4 o;
        o.x = (uint)f32_to_bf16(a.x) | ((uint)f32_to_bf16(a.y) << 16);
        o.y = (uint)f32_to_bf16(a.z) | ((uint)f32_to_bf16(a.w) << 16);
        o.z = (uint)f32_to_bf16(b.x) | ((uint)f32_to_bf16(b.y) << 16);
        o.w = (uint)f32_to_bf16(b.z) | ((uint)f32_to_bf16(b.w) << 16);
        ((uint4*)out)[i] = o;
    }
}

// -------------------------------- W[K][N] f32 -> Wt[N][K] bf16, z picks matrix
__global__ void transpose_cast2(const float* __restrict__ W0, ushort* __restrict__ T0,
                                const float* __restrict__ W1, ushort* __restrict__ T1,
                                int K, int N) {
    __shared__ float t[32][33];
    const float* W = blockIdx.z ? W1 : W0;
    ushort*     Wt = blockIdx.z ? T1 : T0;
    const int n0 = blockIdx.x * 32, k0 = blockIdx.y * 32;
    const int tx = threadIdx.x, ty = threadIdx.y;   // 32 x 8
#pragma unroll
    for (int i = 0; i < 4; ++i)
        t[ty + 8 * i][tx] = W[(size_t)(k0 + ty + 8 * i) * N + n0 + tx];
    __syncthreads();
#pragma unroll
    for (int i = 0; i < 4; ++i)
        Wt[(size_t)(n0 + ty + 8 * i) * K + k0 + tx] = f32_to_bf16(t[tx][ty + 8 * i]);
}

// ------------------------------------------------------------- bf16 MFMA GEMM
// C = A[M][K] @ Bt[N][K]^T + bias. 128(M)x64(N) tile, 4 waves stacked in M.
// MODE: 0 = bf16 out, 1 = f32 out, 2 = bf16 transposed out (V^T[N][S_LEN]).
template <int MODE>
__device__ __forceinline__ void gemm_body_128x64(
        const ushort* __restrict__ A, const ushort* __restrict__ Bt,
        const float* __restrict__ bias, void* __restrict__ Cv,
        ushort* As, ushort* Bs, int N, int K) {
    const int tid  = threadIdx.x;
    const int lane = tid & 63, wave = tid >> 6;
    const int l15 = lane & 15, quad = lane >> 4;
    const int row0 = blockIdx.y * 128, col0 = blockIdx.x * 64;

    f32x4 acc[2][4];
#pragma unroll
    for (int i = 0; i < 2; ++i)
#pragma unroll
        for (int j = 0; j < 4; ++j) { f32x4 z = {0.f,0.f,0.f,0.f}; acc[i][j] = z; }

    const int ar = tid >> 1, ak = (tid & 1) * 16;
    const int br = tid >> 2, bk = (tid & 3) * 8;
    const ushort* aptr = A  + (size_t)(row0 + ar) * K + ak;
    const ushort* bptr = Bt + (size_t)(col0 + br) * K + bk;

    bf16x8 a0 = *(const bf16x8*)(aptr);
    bf16x8 a1 = *(const bf16x8*)(aptr + 8);
    bf16x8 b0 = *(const bf16x8*)(bptr);

    for (int k0 = 0; k0 < K; k0 += 32) {
        __syncthreads();
        *(bf16x8*)&As[ar * 40 + ak]     = a0;
        *(bf16x8*)&As[ar * 40 + ak + 8] = a1;
        *(bf16x8*)&Bs[br * 40 + bk]     = b0;
        __syncthreads();

        if (k0 + 32 < K) {
            a0 = *(const bf16x8*)(aptr + k0 + 32);
            a1 = *(const bf16x8*)(aptr + k0 + 40);
            b0 = *(const bf16x8*)(bptr + k0 + 32);
        }

        bf16x8 af[2], bf[4];
#pragma unroll
        for (int mi = 0; mi < 2; ++mi)
            af[mi] = *(const bf16x8*)&As[(wave * 32 + mi * 16 + l15) * 40 + quad * 8];
#pragma unroll
        for (int ni = 0; ni < 4; ++ni)
            bf[ni] = *(const bf16x8*)&Bs[(ni * 16 + l15) * 40 + quad * 8];
#pragma unroll
        for (int mi = 0; mi < 2; ++mi)
#pragma unroll
            for (int ni = 0; ni < 4; ++ni)
                acc[mi][ni] = __builtin_amdgcn_mfma_f32_16x16x32_bf16(
                    af[mi], bf[ni], acc[mi][ni], 0, 0, 0);
    }

#pragma unroll
    for (int mi = 0; mi < 2; ++mi)
#pragma unroll
        for (int ni = 0; ni < 4; ++ni) {
            const int col = col0 + ni * 16 + l15;
            const float bv = bias[col];
            float val[4];
#pragma unroll
            for (int reg = 0; reg < 4; ++reg)
                val[reg] = acc[mi][ni][reg] + bv;
            const int row = row0 + wave * 32 + mi * 16 + quad * 4;
            if (MODE == 0) {
#pragma unroll
                for (int reg = 0; reg < 4; ++reg)
                    ((ushort*)Cv)[(size_t)(row + reg) * N + col] = f32_to_bf16(val[reg]);
            } else if (MODE == 1) {
#pragma unroll
                for (int reg = 0; reg < 4; ++reg)
                    ((float*)Cv)[(size_t)(row + reg) * N + col] = val[reg];
            } else {   // transposed bf16: out[col][row], 4 consecutive rows packed
                uint2 u;
                u.x = (uint)f32_to_bf16(val[0]) | ((uint)f32_to_bf16(val[1]) << 16);
                u.y = (uint)f32_to_bf16(val[2]) | ((uint)f32_to_bf16(val[3]) << 16);
                *(uint2*)&((ushort*)Cv)[(size_t)col * S_LEN + row] = u;
            }
        }
}

// Fused Q/K/V projections. grid (32, 16, 3): z=0 Q (N=2048), z=1 K, z=2 V->V^T.
__global__ __launch_bounds__(256) void gemm_qkv(
        const ushort* __restrict__ Xq, const ushort* __restrict__ Xk,
        const ushort* __restrict__ Xv, const ushort* __restrict__ Wqt,
        const ushort* __restrict__ Wkt, const ushort* __restrict__ Wvt,
        const float* __restrict__ bq, const float* __restrict__ bk,
        const float* __restrict__ bv, ushort* __restrict__ Qb,
        ushort* __restrict__ Kb, ushort* __restrict__ Vtp) {
    const int z = blockIdx.z;
    if (z != 0 && blockIdx.x >= 8) return;     // K/V have N=512 (8 blocks of 64)
    __shared__ ushort As[128 * 40];
    __shared__ ushort Bs[64 * 40];
    if (z == 0)
        gemm_body_128x64<0>(Xq, Wqt, bq, Qb, As, Bs, 2048, DMODEL);
    else if (z == 1)
        gemm_body_128x64<0>(Xk, Wkt, bk, Kb, As, Bs, 512, DMODEL);
    else
        gemm_body_128x64<2>(Xv, Wvt, bv, Vtp, As, Bs, 512, DMODEL);
}

__global__ __launch_bounds__(256) void gemm_out(
        const ushort* __restrict__ A, const ushort* __restrict__ Bt,
        const float* __restrict__ bias, float* __restrict__ C, int N, int K) {
    __shared__ ushort As[128 * 40];
    __shared__ ushort Bs[64 * 40];
    gemm_body_128x64<1>(A, Bt, bias, C, As, Bs, N, K);
}

// ------------------------------------------------------ MFMA flash attention
// Grid (16, 32): block handles q-tiles {bx, 31-bx} of one head, 17 j-chunks of
// 128 keys each (perfect balance). 4 waves; wave owns a 16-row Q stripe.
// exp2-domain online softmax; K [key][d] / V^T [d][key] LDS; reg prefetch.
#define SC_LOG2 (0.125f * 1.4426950408889634f)

__global__ __launch_bounds__(256) void gqa_attn_mfma(
        const ushort* __restrict__ Qb, const ushort* __restrict__ Kb,
        const ushort* __restrict__ Vt, ushort* __restrict__ Ab) {
    __shared__ ushort Ks[128 * 72];      // [key][d], 128 keys
    __shared__ ushort Vs[64 * 136];      // [d][key], 128 keys + pad
    __shared__ ushort Ps[4][16 * 136];   // per-wave P [m][k0..127]

    const int h    = blockIdx.y, g = h >> 2;
    const int tid  = threadIdx.x;
    const int lane = tid & 63, wave = tid >> 6;
    const int l15  = lane & 15, quad = lane >> 4;
    const int NT   = S_LEN / 64;         // 32 q-tiles

    // staging: K 128 rows x 64d (2 thr/row, 4 b128 each); V 64d x 128 keys
    const int krow = tid >> 1, kd = (tid & 1) * 32;
    const int vrow = tid >> 2, vk = (tid & 3) * 32;
    const ushort* kbase = Kb + (size_t)krow * (NG * DK) + g * DK + kd;
    const ushort* vbase = Vt + (size_t)(g * 64 + vrow) * S_LEN + vk;

    for (int sel = 0; sel < 2; ++sel) {
        const int qt = sel ? (NT - 1 - (int)blockIdx.x) : (int)blockIdx.x;
        const int qr = qt * 64 + wave * 16;
        const int nch = (qt >> 1) + 1;       // 128-key chunks needed

        bf16x8 qa0, qa1;
        {
            const size_t base = (size_t)(qr + l15) * (NH * DK) + (size_t)h * DK + quad * 8;
            qa0 = *(const bf16x8*)&Qb[base];
            qa1 = *(const bf16x8*)&Qb[base + 32];
        }

        f32x4 o[4];
#pragma unroll
        for (int dt = 0; dt < 4; ++dt) { f32x4 z = {0.f,0.f,0.f,0.f}; o[dt] = z; }
        float mrow[4] = {-1e30f, -1e30f, -1e30f, -1e30f};
        float lrow[4] = {0.f, 0.f, 0.f, 0.f};

        bf16x8 kr[4], vr[4];
#pragma unroll
        for (int i = 0; i < 4; ++i) {
            kr[i] = *(const bf16x8*)(kbase + i * 8);
            vr[i] = *(const bf16x8*)(vbase + i * 8);
        }

        for (int c = 0; c < nch; ++c) {
            __syncthreads();
#pragma unroll
            for (int i = 0; i < 4; ++i) {
                *(bf16x8*)&Ks[krow * 72 + kd + i * 8]  = kr[i];
                *(bf16x8*)&Vs[vrow * 136 + vk + i * 8] = vr[i];
            }
            __syncthreads();

            if (c + 1 < nch) {
                const size_t ko = (size_t)(c + 1) * 128 * (NG * DK);
                const size_t vo = (size_t)(c + 1) * 128;
#pragma unroll
                for (int i = 0; i < 4; ++i) {
                    kr[i] = *(const bf16x8*)(kbase + ko + i * 8);
                    vr[i] = *(const bf16x8*)(vbase + vo + i * 8);
                }
            }

            // S = Q K^T : 8 key tiles x 2 k-steps
            f32x4 s[8];
#pragma unroll
            for (int kt = 0; kt < 8; ++kt) {
                const bf16x8 kb0 = *(const bf16x8*)&Ks[(kt * 16 + l15) * 72 + quad * 8];
                const bf16x8 kb1 = *(const bf16x8*)&Ks[(kt * 16 + l15) * 72 + 32 + quad * 8];
                f32x4 acc = {0.f, 0.f, 0.f, 0.f};
                acc = __builtin_amdgcn_mfma_f32_16x16x32_bf16(qa0, kb0, acc, 0, 0, 0);
                acc = __builtin_amdgcn_mfma_f32_16x16x32_bf16(qa1, kb1, acc, 0, 0, 0);
                s[kt] = acc;
            }

            // scale into log2 domain + causal mask (last chunk only)
            if (c == nch - 1) {
#pragma unroll
                for (int kt = 0; kt < 8; ++kt)
#pragma unroll
                    for (int r = 0; r < 4; ++r) {
                        const int key = c * 128 + kt * 16 + l15;
                        const int row = qr + quad * 4 + r;
                        s[kt][r] = (key <= row) ? s[kt][r] * SC_LOG2 : -1e30f;
                    }
            } else {
#pragma unroll
                for (int kt = 0; kt < 8; ++kt)
#pragma unroll
                    for (int r = 0; r < 4; ++r) s[kt][r] *= SC_LOG2;
            }

            // online softmax in log2 domain (row = quad*4 + r)
            float rmax[4];
#pragma unroll
            for (int r = 0; r < 4; ++r) {
                float m01 = fmaxf(s[0][r], s[1][r]), m23 = fmaxf(s[2][r], s[3][r]);
                float m45 = fmaxf(s[4][r], s[5][r]), m67 = fmaxf(s[6][r], s[7][r]);
                rmax[r] = fmaxf(fmaxf(m01, m23), fmaxf(m45, m67));
            }
#pragma unroll
            for (int off = 1; off <= 8; off <<= 1)
#pragma unroll
                for (int r = 0; r < 4; ++r)
                    rmax[r] = fmaxf(rmax[r], __shfl_xor(rmax[r], off, 64));

            float alpha[4];
#pragma unroll
            for (int r = 0; r < 4; ++r) {
                const float mn = fmaxf(mrow[r], rmax[r]);
                alpha[r] = exp2f(mrow[r] - mn);
                mrow[r] = mn;
            }

            float rsum[4];
#pragma unroll
            for (int kt = 0; kt < 8; ++kt)
#pragma unroll
                for (int r = 0; r < 4; ++r)
                    s[kt][r] = exp2f(s[kt][r] - mrow[r]);   // p in place
#pragma unroll
            for (int r = 0; r < 4; ++r)
                rsum[r] = ((s[0][r] + s[1][r]) + (s[2][r] + s[3][r]))
                        + ((s[4][r] + s[5][r]) + (s[6][r] + s[7][r]));
#pragma unroll
            for (int off = 1; off <= 8; off <<= 1)
#pragma unroll
                for (int r = 0; r < 4; ++r)
                    rsum[r] += __shfl_xor(rsum[r], off, 64);
#pragma unroll
            for (int r = 0; r < 4; ++r)
                lrow[r] = lrow[r] * alpha[r] + rsum[r];
#pragma unroll
            for (int dt = 0; dt < 4; ++dt)
#pragma unroll
                for (int r = 0; r < 4; ++r)
                    o[dt][r] *= alpha[r];

            // P: C-layout -> A-layout via per-wave LDS region
            ushort* Pw = &Ps[wave][0];
#pragma unroll
            for (int kt = 0; kt < 8; ++kt)
#pragma unroll
                for (int r = 0; r < 4; ++r)
                    Pw[(quad * 4 + r) * 136 + kt * 16 + l15] = f32_to_bf16(s[kt][r]);
            bf16x8 pa[4];
#pragma unroll
            for (int ks = 0; ks < 4; ++ks)
                pa[ks] = *(const bf16x8*)&Pw[l15 * 136 + ks * 32 + quad * 8];

            // O += P V : 4 d tiles x 4 key-steps
#pragma unroll
            for (int dt = 0; dt < 4; ++dt)
#pragma unroll
                for (int ks = 0; ks < 4; ++ks) {
                    const bf16x8 vb =
                        *(const bf16x8*)&Vs[(dt * 16 + l15) * 136 + ks * 32 + quad * 8];
                    o[dt] = __builtin_amdgcn_mfma_f32_16x16x32_bf16(pa[ks], vb, o[dt], 0, 0, 0);
                }
        }

        float inv[4];
#pragma unroll
        for (int r = 0; r < 4; ++r) inv[r] = 1.0f / lrow[r];
#pragma unroll
        for (int dt = 0; dt < 4; ++dt)
#pragma unroll
            for (int r = 0; r < 4; ++r)
                Ab[(size_t)(qr + quad * 4 + r) * (NH * DV) + (size_t)h * DV + dt * 16 + l15] =
                    f32_to_bf16(o[dt][r] * inv[r]);
        __syncthreads();   // protect LDS before second tile of the pair
    }
}

// ---------------------------------------------------------------------------
extern "C" void kernel_launch(void* const* d_in, const int* in_sizes, int n_in,
                              void* d_out, int out_size, void* d_ws, size_t ws_size,
                              hipStream_t stream) {
    const float* queries = (const float*)d_in[0];
    const float* keys    = (const float*)d_in[1];
    const float* values  = (const float*)d_in[2];
    const float* Wq      = (const float*)d_in[3];
    const float* bq      = (const float*)d_in[4];
    const float* Wk      = (const float*)d_in[5];
    const float* bk      = (const float*)d_in[6];
    const float* Wv      = (const float*)d_in[7];
    const float* bv      = (const float*)d_in[8];
    const float* Wo      = (const float*)d_in[9];
    const float* bo      = (const float*)d_in[10];
    float* out = (float*)d_out;

    const size_t MB = 1024 * 1024;
    unsigned char* w = (unsigned char*)d_ws;
    ushort* Xq  = (ushort*)(w + 0 * MB);    // [2048][2048] bf16
    ushort* Xk  = (ushort*)(w + 8 * MB);
    ushort* Xv  = (ushort*)(w + 16 * MB);
    ushort* Wqt = (ushort*)(w + 24 * MB);   // [2048][2048]
    ushort* Wkt = (ushort*)(w + 32 * MB);   // [512][2048]
    ushort* Wvt = (ushort*)(w + 34 * MB);
    ushort* Wot = (ushort*)(w + 36 * MB);   // [2048][2048]
    ushort* Qb  = (ushort*)(w + 44 * MB);   // [2048][2048]
    ushort* Kb  = (ushort*)(w + 52 * MB);   // [2048][512]
    ushort* Vtp = (ushort*)(w + 54 * MB);   // V^T [512][2048]
    ushort* Ab  = (ushort*)(w + 56 * MB);   // [2048][2048]

    const int n8 = (S_LEN * DMODEL) / 8;
    cast3_f32_to_bf16<<<dim3(512, 1, 3), 256, 0, stream>>>(
        queries, keys, values, Xq, Xk, Xv, n8);

    dim3 tb(32, 8);
    transpose_cast2<<<dim3(2048 / 32, 2048 / 32, 2), tb, 0, stream>>>(
        Wq, Wqt, Wo, Wot, DMODEL, 2048);
    transpose_cast2<<<dim3(512 / 32, 2048 / 32, 2), tb, 0, stream>>>(
        Wk, Wkt, Wv, Wvt, DMODEL, 512);

    // fused Q/K/V projections (V written directly as V^T)
    gemm_qkv<<<dim3(32, 16, 3), 256, 0, stream>>>(
        Xq, Xk, Xv, Wqt, Wkt, Wvt, bq, bk, bv, Qb, Kb, Vtp);

    // attention: paired q-tiles, 128-key chunks
    gqa_attn_mfma<<<dim3(16, 32), 256, 0, stream>>>(Qb, Kb, Vtp, Ab);

    // O projection -> f32 out
    gemm_out<<<dim3(32, 16), 256, 0, stream>>>(Ab, Wot, bo, out, 2048, DMODEL);
}